// Round 1
// baseline (213.835 us; speedup 1.0000x reference)
//
#include <hip/hip_runtime.h>
#include <hip/hip_bf16.h>

#define EPS 1e-6f

__device__ __forceinline__ float3 ld3(const float* p, int i) {
    return make_float3(p[3*i+0], p[3*i+1], p[3*i+2]);
}

__device__ __forceinline__ float3 add3(float3 a, float3 b) {
    return make_float3(a.x+b.x, a.y+b.y, a.z+b.z);
}
__device__ __forceinline__ float3 sub3(float3 a, float3 b) {
    return make_float3(a.x-b.x, a.y-b.y, a.z-b.z);
}
__device__ __forceinline__ float3 scale3(float s, float3 a) {
    return make_float3(s*a.x, s*a.y, s*a.z);
}
__device__ __forceinline__ float dot3(float3 a, float3 b) {
    return a.x*b.x + a.y*b.y + a.z*b.z;
}
__device__ __forceinline__ float3 norm3(float3 a) {
    float n = sqrtf(dot3(a, a));
    float inv = 1.0f / fmaxf(n, EPS);
    return scale3(inv, a);
}

__global__ __launch_bounds__(256) void phong_kernel(
    const int* __restrict__ p2f,        // (N,H,W,1)
    const float* __restrict__ bary,     // (N,H,W,1,3)
    const float* __restrict__ verts,    // (V,3)
    const float* __restrict__ vnorm,    // (V,3)
    const float* __restrict__ vcol,     // (V,3)
    const int* __restrict__ faces,      // (F,3)
    const float* __restrict__ light_loc,// (N,3)
    const float* __restrict__ l_amb,    // (1,3)
    const float* __restrict__ l_diff,   // (1,3)
    const float* __restrict__ l_spec,   // (1,3)
    const float* __restrict__ m_amb,    // (1,3)
    const float* __restrict__ m_diff,   // (1,3)
    const float* __restrict__ m_spec,   // (1,3)
    const float* __restrict__ shin,     // (1,)
    const float* __restrict__ cam,      // (N,3)
    const float* __restrict__ bg,       // (3,)
    float* __restrict__ out,            // (N,H,W,4)
    int total, int hw)
{
    int idx = blockIdx.x * blockDim.x + threadIdx.x;
    if (idx >= total) return;

    int f = p2f[idx];
    float4 o;
    if (f < 0) {
        o = make_float4(bg[0], bg[1], bg[2], 0.0f);
    } else {
        float b0 = bary[3*idx+0];
        float b1 = bary[3*idx+1];
        float b2 = bary[3*idx+2];
        int v0 = faces[3*f+0];
        int v1 = faces[3*f+1];
        int v2 = faces[3*f+2];

        // interpolate position, normal, color
        float3 p = add3(add3(scale3(b0, ld3(verts, v0)),
                             scale3(b1, ld3(verts, v1))),
                             scale3(b2, ld3(verts, v2)));
        float3 nr = add3(add3(scale3(b0, ld3(vnorm, v0)),
                              scale3(b1, ld3(vnorm, v1))),
                              scale3(b2, ld3(vnorm, v2)));
        float3 tx = add3(add3(scale3(b0, ld3(vcol, v0)),
                              scale3(b1, ld3(vcol, v1))),
                              scale3(b2, ld3(vcol, v2)));

        int n_b = (unsigned)idx / (unsigned)hw;   // batch index
        float3 loc = ld3(light_loc, n_b);
        float3 cm  = ld3(cam, n_b);

        float3 n  = norm3(nr);
        float3 tl = norm3(sub3(loc, p));
        float cos_angle = dot3(n, tl);
        float cos_pos = fmaxf(cos_angle, 0.0f);
        float smask = (cos_angle > 0.0f) ? 1.0f : 0.0f;
        float cos_m = cos_angle * smask;

        float3 vd = norm3(sub3(cm, p));
        float3 refl = add3(scale3(-1.0f, tl), scale3(2.0f * cos_m, n));
        float alpha = fmaxf(dot3(vd, refl), 0.0f) * smask;
        float spec_pow = (alpha > 0.0f) ? powf(alpha, shin[0]) : 0.0f;

        float la0 = l_amb[0], la1 = l_amb[1], la2 = l_amb[2];
        float ld0 = l_diff[0], ld1 = l_diff[1], ld2 = l_diff[2];
        float ls0 = l_spec[0], ls1 = l_spec[1], ls2 = l_spec[2];
        float ma0 = m_amb[0], ma1 = m_amb[1], ma2 = m_amb[2];
        float md0 = m_diff[0], md1 = m_diff[1], md2 = m_diff[2];
        float ms0 = m_spec[0], ms1 = m_spec[1], ms2 = m_spec[2];

        float c0 = (ma0*la0 + md0*ld0*cos_pos) * tx.x + ms0*ls0*spec_pow;
        float c1 = (ma1*la1 + md1*ld1*cos_pos) * tx.y + ms1*ls1*spec_pow;
        float c2 = (ma2*la2 + md2*ld2*cos_pos) * tx.z + ms2*ls2*spec_pow;
        o = make_float4(c0, c1, c2, 1.0f);
    }
    reinterpret_cast<float4*>(out)[idx] = o;
}

extern "C" void kernel_launch(void* const* d_in, const int* in_sizes, int n_in,
                              void* d_out, int out_size, void* d_ws, size_t ws_size,
                              hipStream_t stream) {
    const int*   p2f       = (const int*)  d_in[0];
    const float* bary      = (const float*)d_in[1];
    const float* verts     = (const float*)d_in[2];
    const float* vnorm     = (const float*)d_in[3];
    const float* vcol      = (const float*)d_in[4];
    const int*   faces     = (const int*)  d_in[5];
    const float* light_loc = (const float*)d_in[6];
    const float* l_amb     = (const float*)d_in[7];
    const float* l_diff    = (const float*)d_in[8];
    const float* l_spec    = (const float*)d_in[9];
    const float* m_amb     = (const float*)d_in[10];
    const float* m_diff    = (const float*)d_in[11];
    const float* m_spec    = (const float*)d_in[12];
    const float* shin      = (const float*)d_in[13];
    const float* cam       = (const float*)d_in[14];
    const float* bg        = (const float*)d_in[15];
    float* out = (float*)d_out;

    int total = in_sizes[0];               // N*H*W*K pixels (K=1)
    int n_batch = in_sizes[6] / 3;         // N from light_location
    int hw = total / n_batch;              // H*W*K

    int block = 256;
    int grid = (total + block - 1) / block;
    phong_kernel<<<grid, block, 0, stream>>>(
        p2f, bary, verts, vnorm, vcol, faces, light_loc,
        l_amb, l_diff, l_spec, m_amb, m_diff, m_spec, shin, cam, bg,
        out, total, hw);
}

// Round 2
// 191.013 us; speedup vs baseline: 1.1195x; 1.1195x over previous
//
#include <hip/hip_runtime.h>
#include <hip/hip_bf16.h>

#define EPS 1e-6f

__device__ __forceinline__ float3 ld3(const float* p, int i) {
    return make_float3(p[3*i+0], p[3*i+1], p[3*i+2]);
}
__device__ __forceinline__ float3 add3(float3 a, float3 b) {
    return make_float3(a.x+b.x, a.y+b.y, a.z+b.z);
}
__device__ __forceinline__ float3 sub3(float3 a, float3 b) {
    return make_float3(a.x-b.x, a.y-b.y, a.z-b.z);
}
__device__ __forceinline__ float3 scale3(float s, float3 a) {
    return make_float3(s*a.x, s*a.y, s*a.z);
}
__device__ __forceinline__ float dot3(float3 a, float3 b) {
    return a.x*b.x + a.y*b.y + a.z*b.z;
}
__device__ __forceinline__ float3 norm3(float3 a) {
    float n = sqrtf(dot3(a, a));
    float inv = 1.0f / fmaxf(n, EPS);
    return scale3(inv, a);
}

// ---------------- Pass 1: face-major gather into packed 112B records ----------
// Record layout (28 floats): p0 p1 p2 | n0 n1 n2 | c0 c1 c2 | pad
__global__ __launch_bounds__(256) void gather_faces_kernel(
    const float* __restrict__ verts,
    const float* __restrict__ vnorm,
    const float* __restrict__ vcol,
    const int* __restrict__ faces,
    float* __restrict__ fa,   // F * 28 floats
    int F)
{
    int f = blockIdx.x * blockDim.x + threadIdx.x;
    if (f >= F) return;
    int v0 = faces[3*f+0];
    int v1 = faces[3*f+1];
    int v2 = faces[3*f+2];

    float3 p0 = ld3(verts, v0), p1 = ld3(verts, v1), p2 = ld3(verts, v2);
    float3 n0 = ld3(vnorm, v0), n1 = ld3(vnorm, v1), n2 = ld3(vnorm, v2);
    float3 c0 = ld3(vcol,  v0), c1 = ld3(vcol,  v1), c2 = ld3(vcol,  v2);

    float4* r = reinterpret_cast<float4*>(fa + 28*f);
    r[0] = make_float4(p0.x, p0.y, p0.z, p1.x);
    r[1] = make_float4(p1.y, p1.z, p2.x, p2.y);
    r[2] = make_float4(p2.z, n0.x, n0.y, n0.z);
    r[3] = make_float4(n1.x, n1.y, n1.z, n2.x);
    r[4] = make_float4(n2.y, n2.z, c0.x, c0.y);
    r[5] = make_float4(c0.z, c1.x, c1.y, c1.z);
    r[6] = make_float4(c2.x, c2.y, c2.z, 0.0f);
}

// ---------------- Pass 2: pixel-major shade, reads one packed record ----------
__global__ __launch_bounds__(256) void phong_kernel2(
    const int* __restrict__ p2f,
    const float* __restrict__ bary,
    const float* __restrict__ fa,       // packed face records
    const float* __restrict__ light_loc,
    const float* __restrict__ l_amb,
    const float* __restrict__ l_diff,
    const float* __restrict__ l_spec,
    const float* __restrict__ m_amb,
    const float* __restrict__ m_diff,
    const float* __restrict__ m_spec,
    const float* __restrict__ shin,
    const float* __restrict__ cam,
    const float* __restrict__ bg,
    float* __restrict__ out,
    int total, int hw)
{
    int idx = blockIdx.x * blockDim.x + threadIdx.x;
    if (idx >= total) return;

    int f = p2f[idx];
    float4 o;
    if (f < 0) {
        o = make_float4(bg[0], bg[1], bg[2], 0.0f);
    } else {
        float b0 = bary[3*idx+0];
        float b1 = bary[3*idx+1];
        float b2 = bary[3*idx+2];

        const float4* r = reinterpret_cast<const float4*>(fa + 28*f);
        float4 q0 = r[0], q1 = r[1], q2 = r[2], q3 = r[3],
               q4 = r[4], q5 = r[5], q6 = r[6];

        float3 p0 = make_float3(q0.x, q0.y, q0.z);
        float3 p1 = make_float3(q0.w, q1.x, q1.y);
        float3 p2 = make_float3(q1.z, q1.w, q2.x);
        float3 n0 = make_float3(q2.y, q2.z, q2.w);
        float3 n1 = make_float3(q3.x, q3.y, q3.z);
        float3 n2 = make_float3(q3.w, q4.x, q4.y);
        float3 c0 = make_float3(q4.z, q4.w, q5.x);
        float3 c1 = make_float3(q5.y, q5.z, q5.w);
        float3 c2 = make_float3(q6.x, q6.y, q6.z);

        float3 p  = add3(add3(scale3(b0, p0), scale3(b1, p1)), scale3(b2, p2));
        float3 nr = add3(add3(scale3(b0, n0), scale3(b1, n1)), scale3(b2, n2));
        float3 tx = add3(add3(scale3(b0, c0), scale3(b1, c1)), scale3(b2, c2));

        int n_b = (unsigned)idx / (unsigned)hw;
        float3 loc = ld3(light_loc, n_b);
        float3 cm  = ld3(cam, n_b);

        float3 n  = norm3(nr);
        float3 tl = norm3(sub3(loc, p));
        float cos_angle = dot3(n, tl);
        float cos_pos = fmaxf(cos_angle, 0.0f);
        float smask = (cos_angle > 0.0f) ? 1.0f : 0.0f;
        float cos_m = cos_angle * smask;

        float3 vd = norm3(sub3(cm, p));
        float3 refl = add3(scale3(-1.0f, tl), scale3(2.0f * cos_m, n));
        float alpha = fmaxf(dot3(vd, refl), 0.0f) * smask;
        float spec_pow = (alpha > 0.0f) ? powf(alpha, shin[0]) : 0.0f;

        float c0o = (m_amb[0]*l_amb[0] + m_diff[0]*l_diff[0]*cos_pos) * tx.x + m_spec[0]*l_spec[0]*spec_pow;
        float c1o = (m_amb[1]*l_amb[1] + m_diff[1]*l_diff[1]*cos_pos) * tx.y + m_spec[1]*l_spec[1]*spec_pow;
        float c2o = (m_amb[2]*l_amb[2] + m_diff[2]*l_diff[2]*cos_pos) * tx.z + m_spec[2]*l_spec[2]*spec_pow;
        o = make_float4(c0o, c1o, c2o, 1.0f);
    }
    reinterpret_cast<float4*>(out)[idx] = o;
}

// ---------------- Fallback single-pass (if ws too small) ----------------------
__global__ __launch_bounds__(256) void phong_kernel1(
    const int* __restrict__ p2f,
    const float* __restrict__ bary,
    const float* __restrict__ verts,
    const float* __restrict__ vnorm,
    const float* __restrict__ vcol,
    const int* __restrict__ faces,
    const float* __restrict__ light_loc,
    const float* __restrict__ l_amb,
    const float* __restrict__ l_diff,
    const float* __restrict__ l_spec,
    const float* __restrict__ m_amb,
    const float* __restrict__ m_diff,
    const float* __restrict__ m_spec,
    const float* __restrict__ shin,
    const float* __restrict__ cam,
    const float* __restrict__ bg,
    float* __restrict__ out,
    int total, int hw)
{
    int idx = blockIdx.x * blockDim.x + threadIdx.x;
    if (idx >= total) return;

    int f = p2f[idx];
    float4 o;
    if (f < 0) {
        o = make_float4(bg[0], bg[1], bg[2], 0.0f);
    } else {
        float b0 = bary[3*idx+0];
        float b1 = bary[3*idx+1];
        float b2 = bary[3*idx+2];
        int v0 = faces[3*f+0];
        int v1 = faces[3*f+1];
        int v2 = faces[3*f+2];

        float3 p = add3(add3(scale3(b0, ld3(verts, v0)),
                             scale3(b1, ld3(verts, v1))),
                             scale3(b2, ld3(verts, v2)));
        float3 nr = add3(add3(scale3(b0, ld3(vnorm, v0)),
                              scale3(b1, ld3(vnorm, v1))),
                              scale3(b2, ld3(vnorm, v2)));
        float3 tx = add3(add3(scale3(b0, ld3(vcol, v0)),
                              scale3(b1, ld3(vcol, v1))),
                              scale3(b2, ld3(vcol, v2)));

        int n_b = (unsigned)idx / (unsigned)hw;
        float3 loc = ld3(light_loc, n_b);
        float3 cm  = ld3(cam, n_b);

        float3 n  = norm3(nr);
        float3 tl = norm3(sub3(loc, p));
        float cos_angle = dot3(n, tl);
        float cos_pos = fmaxf(cos_angle, 0.0f);
        float smask = (cos_angle > 0.0f) ? 1.0f : 0.0f;
        float cos_m = cos_angle * smask;

        float3 vd = norm3(sub3(cm, p));
        float3 refl = add3(scale3(-1.0f, tl), scale3(2.0f * cos_m, n));
        float alpha = fmaxf(dot3(vd, refl), 0.0f) * smask;
        float spec_pow = (alpha > 0.0f) ? powf(alpha, shin[0]) : 0.0f;

        float c0o = (m_amb[0]*l_amb[0] + m_diff[0]*l_diff[0]*cos_pos) * tx.x + m_spec[0]*l_spec[0]*spec_pow;
        float c1o = (m_amb[1]*l_amb[1] + m_diff[1]*l_diff[1]*cos_pos) * tx.y + m_spec[1]*l_spec[1]*spec_pow;
        float c2o = (m_amb[2]*l_amb[2] + m_diff[2]*l_diff[2]*cos_pos) * tx.z + m_spec[2]*l_spec[2]*spec_pow;
        o = make_float4(c0o, c1o, c2o, 1.0f);
    }
    reinterpret_cast<float4*>(out)[idx] = o;
}

extern "C" void kernel_launch(void* const* d_in, const int* in_sizes, int n_in,
                              void* d_out, int out_size, void* d_ws, size_t ws_size,
                              hipStream_t stream) {
    const int*   p2f       = (const int*)  d_in[0];
    const float* bary      = (const float*)d_in[1];
    const float* verts     = (const float*)d_in[2];
    const float* vnorm     = (const float*)d_in[3];
    const float* vcol      = (const float*)d_in[4];
    const int*   faces     = (const int*)  d_in[5];
    const float* light_loc = (const float*)d_in[6];
    const float* l_amb     = (const float*)d_in[7];
    const float* l_diff    = (const float*)d_in[8];
    const float* l_spec    = (const float*)d_in[9];
    const float* m_amb     = (const float*)d_in[10];
    const float* m_diff    = (const float*)d_in[11];
    const float* m_spec    = (const float*)d_in[12];
    const float* shin      = (const float*)d_in[13];
    const float* cam       = (const float*)d_in[14];
    const float* bg        = (const float*)d_in[15];
    float* out = (float*)d_out;

    int total   = in_sizes[0];         // N*H*W*K pixels (K=1)
    int n_batch = in_sizes[6] / 3;     // N
    int hw      = total / n_batch;     // H*W*K
    int F       = in_sizes[5] / 3;     // faces

    int block = 256;
    size_t needed = (size_t)F * 28 * sizeof(float);

    if (ws_size >= needed) {
        float* fa = (float*)d_ws;
        int grid1 = (F + block - 1) / block;
        gather_faces_kernel<<<grid1, block, 0, stream>>>(verts, vnorm, vcol, faces, fa, F);
        int grid2 = (total + block - 1) / block;
        phong_kernel2<<<grid2, block, 0, stream>>>(
            p2f, bary, fa, light_loc,
            l_amb, l_diff, l_spec, m_amb, m_diff, m_spec, shin, cam, bg,
            out, total, hw);
    } else {
        int grid = (total + block - 1) / block;
        phong_kernel1<<<grid, block, 0, stream>>>(
            p2f, bary, verts, vnorm, vcol, faces, light_loc,
            l_amb, l_diff, l_spec, m_amb, m_diff, m_spec, shin, cam, bg,
            out, total, hw);
    }
}

// Round 4
// 179.309 us; speedup vs baseline: 1.1926x; 1.0653x over previous
//
#include <hip/hip_runtime.h>

#define EPS 1e-6f

__device__ __forceinline__ float3 ld3(const float* p, int i) {
    return make_float3(p[3*i+0], p[3*i+1], p[3*i+2]);
}
__device__ __forceinline__ float3 add3(float3 a, float3 b) {
    return make_float3(a.x+b.x, a.y+b.y, a.z+b.z);
}
__device__ __forceinline__ float3 sub3(float3 a, float3 b) {
    return make_float3(a.x-b.x, a.y-b.y, a.z-b.z);
}
__device__ __forceinline__ float3 scale3(float s, float3 a) {
    return make_float3(s*a.x, s*a.y, s*a.z);
}
__device__ __forceinline__ float dot3(float3 a, float3 b) {
    return a.x*b.x + a.y*b.y + a.z*b.z;
}
__device__ __forceinline__ float3 norm3(float3 a) {
    float n = sqrtf(dot3(a, a));
    float inv = 1.0f / fmaxf(n, EPS);
    return scale3(inv, a);
}

// Record: 27 fp32 payload in 7 float4 (112 B used); stride is 7 or 8 float4.
// f[0..2]=p0 f[3..5]=p1 f[6..8]=p2 | f[9..17]=n0,n1,n2 | f[18..26]=c0,c1,c2
union Rec {
    float4 q[7];
    float  f[28];
};

// ---------------- Pass 1: face-major gather into packed fp32 records ---------
__global__ __launch_bounds__(256) void gather_faces_kernel(
    const float* __restrict__ verts,
    const float* __restrict__ vnorm,
    const float* __restrict__ vcol,
    const int* __restrict__ faces,
    float4* __restrict__ fa,
    int F, int stride)          // stride in float4 units (7 or 8)
{
    int f = blockIdx.x * blockDim.x + threadIdx.x;
    if (f >= F) return;
    int v0 = faces[3*f+0];
    int v1 = faces[3*f+1];
    int v2 = faces[3*f+2];

    Rec u;
#define PUT3(base, src, vi) \
    u.f[base+0] = src[3*vi+0]; \
    u.f[base+1] = src[3*vi+1]; \
    u.f[base+2] = src[3*vi+2];
    PUT3(0,  verts, v0)  PUT3(3,  verts, v1)  PUT3(6,  verts, v2)
    PUT3(9,  vnorm, v0)  PUT3(12, vnorm, v1)  PUT3(15, vnorm, v2)
    PUT3(18, vcol,  v0)  PUT3(21, vcol,  v1)  PUT3(24, vcol,  v2)
#undef PUT3
    u.f[27] = 0.0f;

    float4* r = fa + (size_t)f * stride;
#pragma unroll
    for (int i = 0; i < 7; ++i) r[i] = u.q[i];
}

// ---------------- Pass 2: pixel-major shade, 2 px/thread, branchless gather --
__global__ __launch_bounds__(256) void phong_kernel2(
    const int* __restrict__ p2f,
    const float* __restrict__ bary,
    const float4* __restrict__ fa,
    const float* __restrict__ light_loc,
    const float* __restrict__ l_amb,
    const float* __restrict__ l_diff,
    const float* __restrict__ l_spec,
    const float* __restrict__ m_amb,
    const float* __restrict__ m_diff,
    const float* __restrict__ m_spec,
    const float* __restrict__ shin,
    const float* __restrict__ cam,
    const float* __restrict__ bg,
    float* __restrict__ out,
    int total, int hw, int stride)
{
    int t = blockIdx.x * blockDim.x + threadIdx.x;
    int i0 = 2*t;
    if (i0 >= total) return;

    int2 ff = *reinterpret_cast<const int2*>(p2f + i0);
    float2 ba = *reinterpret_cast<const float2*>(bary + 3*i0 + 0);
    float2 bb = *reinterpret_cast<const float2*>(bary + 3*i0 + 2);
    float2 bc = *reinterpret_cast<const float2*>(bary + 3*i0 + 4);

    int g0 = ff.x < 0 ? 0 : ff.x;
    int g1 = ff.y < 0 ? 0 : ff.y;

    const float4* r0p = fa + (size_t)g0 * stride;
    const float4* r1p = fa + (size_t)g1 * stride;
    Rec r0, r1;
#pragma unroll
    for (int i = 0; i < 7; ++i) r0.q[i] = r0p[i];
#pragma unroll
    for (int i = 0; i < 7; ++i) r1.q[i] = r1p[i];

    int n_b = (unsigned)i0 / (unsigned)hw;
    float3 loc = ld3(light_loc, n_b);
    float3 cm  = ld3(cam, n_b);

    float la0 = l_amb[0], la1 = l_amb[1], la2 = l_amb[2];
    float ld0 = l_diff[0], ld1 = l_diff[1], ld2 = l_diff[2];
    float ls0 = l_spec[0], ls1 = l_spec[1], ls2 = l_spec[2];
    float ma0 = m_amb[0], ma1 = m_amb[1], ma2 = m_amb[2];
    float md0 = m_diff[0], md1 = m_diff[1], md2 = m_diff[2];
    float ms0 = m_spec[0], ms1 = m_spec[1], ms2 = m_spec[2];
    float sh  = shin[0];
    float bg0 = bg[0], bg1 = bg[1], bg2 = bg[2];

    float4 o[2];
    float b0s[2] = {ba.x, bb.y};
    float b1s[2] = {ba.y, bc.x};
    float b2s[2] = {bb.x, bc.y};
    int fs[2] = {ff.x, ff.y};

#pragma unroll
    for (int k = 0; k < 2; ++k) {
        const float* h = (k == 0) ? r0.f : r1.f;
        float b0 = b0s[k], b1 = b1s[k], b2 = b2s[k];

        float3 p = make_float3(
            b0*h[0] + b1*h[3] + b2*h[6],
            b0*h[1] + b1*h[4] + b2*h[7],
            b0*h[2] + b1*h[5] + b2*h[8]);
        float3 nr = make_float3(
            b0*h[9]  + b1*h[12] + b2*h[15],
            b0*h[10] + b1*h[13] + b2*h[16],
            b0*h[11] + b1*h[14] + b2*h[17]);
        float3 tx = make_float3(
            b0*h[18] + b1*h[21] + b2*h[24],
            b0*h[19] + b1*h[22] + b2*h[25],
            b0*h[20] + b1*h[23] + b2*h[26]);

        float3 n  = norm3(nr);
        float3 tl = norm3(sub3(loc, p));
        float cos_angle = dot3(n, tl);
        float cos_pos = fmaxf(cos_angle, 0.0f);
        float smask = (cos_angle > 0.0f) ? 1.0f : 0.0f;
        float cos_m = cos_angle * smask;

        float3 vd = norm3(sub3(cm, p));
        float3 refl = add3(scale3(-1.0f, tl), scale3(2.0f * cos_m, n));
        float alpha = fmaxf(dot3(vd, refl), 0.0f) * smask;
        float spec_pow = (alpha > 0.0f) ? powf(alpha, sh) : 0.0f;

        float c0o = (ma0*la0 + md0*ld0*cos_pos) * tx.x + ms0*ls0*spec_pow;
        float c1o = (ma1*la1 + md1*ld1*cos_pos) * tx.y + ms1*ls1*spec_pow;
        float c2o = (ma2*la2 + md2*ld2*cos_pos) * tx.z + ms2*ls2*spec_pow;

        bool isbg = fs[k] < 0;
        o[k] = isbg ? make_float4(bg0, bg1, bg2, 0.0f)
                    : make_float4(c0o, c1o, c2o, 1.0f);
    }

    float4* op = reinterpret_cast<float4*>(out + 4*(size_t)i0);
    op[0] = o[0];
    op[1] = o[1];
}

// ---------------- Fallback single-pass (if ws too small) ----------------------
__global__ __launch_bounds__(256) void phong_kernel1(
    const int* __restrict__ p2f,
    const float* __restrict__ bary,
    const float* __restrict__ verts,
    const float* __restrict__ vnorm,
    const float* __restrict__ vcol,
    const int* __restrict__ faces,
    const float* __restrict__ light_loc,
    const float* __restrict__ l_amb,
    const float* __restrict__ l_diff,
    const float* __restrict__ l_spec,
    const float* __restrict__ m_amb,
    const float* __restrict__ m_diff,
    const float* __restrict__ m_spec,
    const float* __restrict__ shin,
    const float* __restrict__ cam,
    const float* __restrict__ bg,
    float* __restrict__ out,
    int total, int hw)
{
    int idx = blockIdx.x * blockDim.x + threadIdx.x;
    if (idx >= total) return;

    int f = p2f[idx];
    float4 o;
    if (f < 0) {
        o = make_float4(bg[0], bg[1], bg[2], 0.0f);
    } else {
        float b0 = bary[3*idx+0];
        float b1 = bary[3*idx+1];
        float b2 = bary[3*idx+2];
        int v0 = faces[3*f+0];
        int v1 = faces[3*f+1];
        int v2 = faces[3*f+2];

        float3 p = add3(add3(scale3(b0, ld3(verts, v0)),
                             scale3(b1, ld3(verts, v1))),
                             scale3(b2, ld3(verts, v2)));
        float3 nr = add3(add3(scale3(b0, ld3(vnorm, v0)),
                              scale3(b1, ld3(vnorm, v1))),
                              scale3(b2, ld3(vnorm, v2)));
        float3 tx = add3(add3(scale3(b0, ld3(vcol, v0)),
                              scale3(b1, ld3(vcol, v1))),
                              scale3(b2, ld3(vcol, v2)));

        int n_b = (unsigned)idx / (unsigned)hw;
        float3 loc = ld3(light_loc, n_b);
        float3 cm  = ld3(cam, n_b);

        float3 n  = norm3(nr);
        float3 tl = norm3(sub3(loc, p));
        float cos_angle = dot3(n, tl);
        float cos_pos = fmaxf(cos_angle, 0.0f);
        float smask = (cos_angle > 0.0f) ? 1.0f : 0.0f;
        float cos_m = cos_angle * smask;

        float3 vd = norm3(sub3(cm, p));
        float3 refl = add3(scale3(-1.0f, tl), scale3(2.0f * cos_m, n));
        float alpha = fmaxf(dot3(vd, refl), 0.0f) * smask;
        float spec_pow = (alpha > 0.0f) ? powf(alpha, shin[0]) : 0.0f;

        float c0o = (m_amb[0]*l_amb[0] + m_diff[0]*l_diff[0]*cos_pos) * tx.x + m_spec[0]*l_spec[0]*spec_pow;
        float c1o = (m_amb[1]*l_amb[1] + m_diff[1]*l_diff[1]*cos_pos) * tx.y + m_spec[1]*l_spec[1]*spec_pow;
        float c2o = (m_amb[2]*l_amb[2] + m_diff[2]*l_diff[2]*cos_pos) * tx.z + m_spec[2]*l_spec[2]*spec_pow;
        o = make_float4(c0o, c1o, c2o, 1.0f);
    }
    reinterpret_cast<float4*>(out)[idx] = o;
}

extern "C" void kernel_launch(void* const* d_in, const int* in_sizes, int n_in,
                              void* d_out, int out_size, void* d_ws, size_t ws_size,
                              hipStream_t stream) {
    const int*   p2f       = (const int*)  d_in[0];
    const float* bary      = (const float*)d_in[1];
    const float* verts     = (const float*)d_in[2];
    const float* vnorm     = (const float*)d_in[3];
    const float* vcol      = (const float*)d_in[4];
    const int*   faces     = (const int*)  d_in[5];
    const float* light_loc = (const float*)d_in[6];
    const float* l_amb     = (const float*)d_in[7];
    const float* l_diff    = (const float*)d_in[8];
    const float* l_spec    = (const float*)d_in[9];
    const float* m_amb     = (const float*)d_in[10];
    const float* m_diff    = (const float*)d_in[11];
    const float* m_spec    = (const float*)d_in[12];
    const float* shin      = (const float*)d_in[13];
    const float* cam       = (const float*)d_in[14];
    const float* bg        = (const float*)d_in[15];
    float* out = (float*)d_out;

    int total   = in_sizes[0];         // N*H*W*K pixels (K=1)
    int n_batch = in_sizes[6] / 3;     // N
    int hw      = total / n_batch;     // H*W*K
    int F       = in_sizes[5] / 3;     // faces

    int block = 256;
    // prefer 128 B-aligned records (1 line per gather); else 112 B; else fallback
    int stride = 0;
    if (ws_size >= (size_t)F * 128) stride = 8;
    else if (ws_size >= (size_t)F * 112) stride = 7;

    if (stride != 0 && (total % 2) == 0) {
        float4* fa = (float4*)d_ws;
        int grid1 = (F + block - 1) / block;
        gather_faces_kernel<<<grid1, block, 0, stream>>>(verts, vnorm, vcol, faces, fa, F, stride);
        int pairs = total / 2;
        int grid2 = (pairs + block - 1) / block;
        phong_kernel2<<<grid2, block, 0, stream>>>(
            p2f, bary, fa, light_loc,
            l_amb, l_diff, l_spec, m_amb, m_diff, m_spec, shin, cam, bg,
            out, total, hw, stride);
    } else {
        int grid = (total + block - 1) / block;
        phong_kernel1<<<grid, block, 0, stream>>>(
            p2f, bary, verts, vnorm, vcol, faces, light_loc,
            l_amb, l_diff, l_spec, m_amb, m_diff, m_spec, shin, cam, bg,
            out, total, hw);
    }
}

// Round 5
// 171.408 us; speedup vs baseline: 1.2475x; 1.0461x over previous
//
#include <hip/hip_runtime.h>

#define EPS 1e-6f

__device__ __forceinline__ float3 ld3(const float* p, int i) {
    return make_float3(p[3*i+0], p[3*i+1], p[3*i+2]);
}
__device__ __forceinline__ float3 add3(float3 a, float3 b) {
    return make_float3(a.x+b.x, a.y+b.y, a.z+b.z);
}
__device__ __forceinline__ float3 sub3(float3 a, float3 b) {
    return make_float3(a.x-b.x, a.y-b.y, a.z-b.z);
}
__device__ __forceinline__ float3 scale3(float s, float3 a) {
    return make_float3(s*a.x, s*a.y, s*a.z);
}
__device__ __forceinline__ float dot3(float3 a, float3 b) {
    return a.x*b.x + a.y*b.y + a.z*b.z;
}
__device__ __forceinline__ float3 norm3(float3 a) {
    float n = sqrtf(dot3(a, a));
    float inv = 1.0f / fmaxf(n, EPS);
    return scale3(inv, a);
}

// ---------------- Pass 1: face-major gather into 128B-aligned fp32 records ---
// word layout: [0..2]=p0 [3..5]=p1 [6..8]=p2 [9..17]=n0,n1,n2 [18..26]=c0,c1,c2
__global__ __launch_bounds__(256) void gather_faces_kernel(
    const float* __restrict__ verts,
    const float* __restrict__ vnorm,
    const float* __restrict__ vcol,
    const int* __restrict__ faces,
    float4* __restrict__ fa,
    int F)                       // stride fixed at 8 float4 (128 B)
{
    int f = blockIdx.x * blockDim.x + threadIdx.x;
    if (f >= F) return;
    int v0 = faces[3*f+0];
    int v1 = faces[3*f+1];
    int v2 = faces[3*f+2];

    union { float4 q[8]; float w[32]; } u;
#define PUT3(base, src, vi) \
    u.w[base+0] = src[3*vi+0]; \
    u.w[base+1] = src[3*vi+1]; \
    u.w[base+2] = src[3*vi+2];
    PUT3(0,  verts, v0)  PUT3(3,  verts, v1)  PUT3(6,  verts, v2)
    PUT3(9,  vnorm, v0)  PUT3(12, vnorm, v1)  PUT3(15, vnorm, v2)
    PUT3(18, vcol,  v0)  PUT3(21, vcol,  v1)  PUT3(24, vcol,  v2)
#undef PUT3
    u.w[27] = 0.f; u.w[28] = 0.f; u.w[29] = 0.f; u.w[30] = 0.f; u.w[31] = 0.f;

    float4* r = fa + (size_t)f * 8;
#pragma unroll
    for (int i = 0; i < 8; ++i) r[i] = u.q[i];
}

// ---------------- Pass 2: wave-cooperative line-granular gather + shade ------
// 1 pixel per lane; 8-lane groups load whole 128B records coalesced into LDS.
#define REC_W 36   // LDS stride in words per record (144 B, 16-B aligned)
__global__ __launch_bounds__(256) void phong_kernel3(
    const int* __restrict__ p2f,
    const float* __restrict__ bary,
    const float4* __restrict__ fa,
    const float* __restrict__ light_loc,
    const float* __restrict__ l_amb,
    const float* __restrict__ l_diff,
    const float* __restrict__ l_spec,
    const float* __restrict__ m_amb,
    const float* __restrict__ m_diff,
    const float* __restrict__ m_spec,
    const float* __restrict__ shin,
    const float* __restrict__ cam,
    const float* __restrict__ bg,
    float* __restrict__ out,
    int total, int hw)
{
    __shared__ float lds[4][64 * REC_W];

    int lane = threadIdx.x & 63;
    int wv   = threadIdx.x >> 6;
    int idx  = blockIdx.x * 256 + wv * 64 + lane;
    // grid sized so idx < total always (total % 256 == 0)

    int f = p2f[idx];
    float b0 = bary[3*idx+0];
    float b1 = bary[3*idx+1];
    float b2 = bary[3*idx+2];
    int g = f < 0 ? 0 : f;

    float* myl = lds[wv];
    int seg = lane & 7;   // 16-B segment within record
    int sub = lane >> 3;  // pixel-within-group-of-8

    // Phase A: cooperative gather — 8 px per instruction, fully coalesced lines
#pragma unroll
    for (int it = 0; it < 8; ++it) {
        int p = it * 8 + sub;                 // pixel 0..63 within wave
        int fp = __shfl(g, p, 64);            // face id for pixel p
        float4 v = fa[(size_t)fp * 8 + seg];
        *reinterpret_cast<float4*>(&myl[p * REC_W + seg * 4]) = v;
    }
    __syncthreads();

    // Phase B: each lane reads its own record from LDS
    union { float4 q[7]; float w[28]; } r;
    const float4* s4 = reinterpret_cast<const float4*>(&myl[lane * REC_W]);
#pragma unroll
    for (int i = 0; i < 7; ++i) r.q[i] = s4[i];
    const float* h = r.w;

    int n_b = (unsigned)idx / (unsigned)hw;
    float3 loc = ld3(light_loc, n_b);
    float3 cm  = ld3(cam, n_b);

    float3 p = make_float3(
        b0*h[0] + b1*h[3] + b2*h[6],
        b0*h[1] + b1*h[4] + b2*h[7],
        b0*h[2] + b1*h[5] + b2*h[8]);
    float3 nr = make_float3(
        b0*h[9]  + b1*h[12] + b2*h[15],
        b0*h[10] + b1*h[13] + b2*h[16],
        b0*h[11] + b1*h[14] + b2*h[17]);
    float3 tx = make_float3(
        b0*h[18] + b1*h[21] + b2*h[24],
        b0*h[19] + b1*h[22] + b2*h[25],
        b0*h[20] + b1*h[23] + b2*h[26]);

    float3 n  = norm3(nr);
    float3 tl = norm3(sub3(loc, p));
    float cos_angle = dot3(n, tl);
    float cos_pos = fmaxf(cos_angle, 0.0f);
    float smask = (cos_angle > 0.0f) ? 1.0f : 0.0f;
    float cos_m = cos_angle * smask;

    float3 vd = norm3(sub3(cm, p));
    float3 refl = add3(scale3(-1.0f, tl), scale3(2.0f * cos_m, n));
    float alpha = fmaxf(dot3(vd, refl), 0.0f) * smask;
    float spec_pow = (alpha > 0.0f) ? powf(alpha, shin[0]) : 0.0f;

    float c0o = (m_amb[0]*l_amb[0] + m_diff[0]*l_diff[0]*cos_pos) * tx.x + m_spec[0]*l_spec[0]*spec_pow;
    float c1o = (m_amb[1]*l_amb[1] + m_diff[1]*l_diff[1]*cos_pos) * tx.y + m_spec[1]*l_spec[1]*spec_pow;
    float c2o = (m_amb[2]*l_amb[2] + m_diff[2]*l_diff[2]*cos_pos) * tx.z + m_spec[2]*l_spec[2]*spec_pow;

    float4 o = (f < 0) ? make_float4(bg[0], bg[1], bg[2], 0.0f)
                       : make_float4(c0o, c1o, c2o, 1.0f);
    reinterpret_cast<float4*>(out)[idx] = o;
}

// ---------------- Fallback single-pass --------------------------------------
__global__ __launch_bounds__(256) void phong_kernel1(
    const int* __restrict__ p2f,
    const float* __restrict__ bary,
    const float* __restrict__ verts,
    const float* __restrict__ vnorm,
    const float* __restrict__ vcol,
    const int* __restrict__ faces,
    const float* __restrict__ light_loc,
    const float* __restrict__ l_amb,
    const float* __restrict__ l_diff,
    const float* __restrict__ l_spec,
    const float* __restrict__ m_amb,
    const float* __restrict__ m_diff,
    const float* __restrict__ m_spec,
    const float* __restrict__ shin,
    const float* __restrict__ cam,
    const float* __restrict__ bg,
    float* __restrict__ out,
    int total, int hw)
{
    int idx = blockIdx.x * blockDim.x + threadIdx.x;
    if (idx >= total) return;

    int f = p2f[idx];
    float4 o;
    if (f < 0) {
        o = make_float4(bg[0], bg[1], bg[2], 0.0f);
    } else {
        float b0 = bary[3*idx+0];
        float b1 = bary[3*idx+1];
        float b2 = bary[3*idx+2];
        int v0 = faces[3*f+0];
        int v1 = faces[3*f+1];
        int v2 = faces[3*f+2];

        float3 p = add3(add3(scale3(b0, ld3(verts, v0)),
                             scale3(b1, ld3(verts, v1))),
                             scale3(b2, ld3(verts, v2)));
        float3 nr = add3(add3(scale3(b0, ld3(vnorm, v0)),
                              scale3(b1, ld3(vnorm, v1))),
                              scale3(b2, ld3(vnorm, v2)));
        float3 tx = add3(add3(scale3(b0, ld3(vcol, v0)),
                              scale3(b1, ld3(vcol, v1))),
                              scale3(b2, ld3(vcol, v2)));

        int n_b = (unsigned)idx / (unsigned)hw;
        float3 loc = ld3(light_loc, n_b);
        float3 cm  = ld3(cam, n_b);

        float3 n  = norm3(nr);
        float3 tl = norm3(sub3(loc, p));
        float cos_angle = dot3(n, tl);
        float cos_pos = fmaxf(cos_angle, 0.0f);
        float smask = (cos_angle > 0.0f) ? 1.0f : 0.0f;
        float cos_m = cos_angle * smask;

        float3 vd = norm3(sub3(cm, p));
        float3 refl = add3(scale3(-1.0f, tl), scale3(2.0f * cos_m, n));
        float alpha = fmaxf(dot3(vd, refl), 0.0f) * smask;
        float spec_pow = (alpha > 0.0f) ? powf(alpha, shin[0]) : 0.0f;

        float c0o = (m_amb[0]*l_amb[0] + m_diff[0]*l_diff[0]*cos_pos) * tx.x + m_spec[0]*l_spec[0]*spec_pow;
        float c1o = (m_amb[1]*l_amb[1] + m_diff[1]*l_diff[1]*cos_pos) * tx.y + m_spec[1]*l_spec[1]*spec_pow;
        float c2o = (m_amb[2]*l_amb[2] + m_diff[2]*l_diff[2]*cos_pos) * tx.z + m_spec[2]*l_spec[2]*spec_pow;
        o = make_float4(c0o, c1o, c2o, 1.0f);
    }
    reinterpret_cast<float4*>(out)[idx] = o;
}

extern "C" void kernel_launch(void* const* d_in, const int* in_sizes, int n_in,
                              void* d_out, int out_size, void* d_ws, size_t ws_size,
                              hipStream_t stream) {
    const int*   p2f       = (const int*)  d_in[0];
    const float* bary      = (const float*)d_in[1];
    const float* verts     = (const float*)d_in[2];
    const float* vnorm     = (const float*)d_in[3];
    const float* vcol      = (const float*)d_in[4];
    const int*   faces     = (const int*)  d_in[5];
    const float* light_loc = (const float*)d_in[6];
    const float* l_amb     = (const float*)d_in[7];
    const float* l_diff    = (const float*)d_in[8];
    const float* l_spec    = (const float*)d_in[9];
    const float* m_amb     = (const float*)d_in[10];
    const float* m_diff    = (const float*)d_in[11];
    const float* m_spec    = (const float*)d_in[12];
    const float* shin      = (const float*)d_in[13];
    const float* cam       = (const float*)d_in[14];
    const float* bg        = (const float*)d_in[15];
    float* out = (float*)d_out;

    int total   = in_sizes[0];         // N*H*W*K pixels (K=1)
    int n_batch = in_sizes[6] / 3;     // N
    int hw      = total / n_batch;     // H*W*K
    int F       = in_sizes[5] / 3;     // faces

    int block = 256;
    bool ws_ok = ws_size >= (size_t)F * 128;

    if (ws_ok && (total % 256) == 0) {
        float4* fa = (float4*)d_ws;
        int grid1 = (F + block - 1) / block;
        gather_faces_kernel<<<grid1, block, 0, stream>>>(verts, vnorm, vcol, faces, fa, F);
        int grid2 = total / 256;
        phong_kernel3<<<grid2, block, 0, stream>>>(
            p2f, bary, fa, light_loc,
            l_amb, l_diff, l_spec, m_amb, m_diff, m_spec, shin, cam, bg,
            out, total, hw);
    } else {
        int grid = (total + block - 1) / block;
        phong_kernel1<<<grid, block, 0, stream>>>(
            p2f, bary, verts, vnorm, vcol, faces, light_loc,
            l_amb, l_diff, l_spec, m_amb, m_diff, m_spec, shin, cam, bg,
            out, total, hw);
    }
}

// Round 7
// 163.424 us; speedup vs baseline: 1.3085x; 1.0489x over previous
//
#include <hip/hip_runtime.h>

#define EPS 1e-6f
#define REC_W 32   // LDS words per record (128 B), XOR-swizzled segments

__device__ __forceinline__ float3 ld3(const float* p, int i) {
    return make_float3(p[3*i+0], p[3*i+1], p[3*i+2]);
}
__device__ __forceinline__ float3 add3(float3 a, float3 b) {
    return make_float3(a.x+b.x, a.y+b.y, a.z+b.z);
}
__device__ __forceinline__ float3 sub3(float3 a, float3 b) {
    return make_float3(a.x-b.x, a.y-b.y, a.z-b.z);
}
__device__ __forceinline__ float3 scale3(float s, float3 a) {
    return make_float3(s*a.x, s*a.y, s*a.z);
}
__device__ __forceinline__ float dot3(float3 a, float3 b) {
    return a.x*b.x + a.y*b.y + a.z*b.z;
}
__device__ __forceinline__ float3 norm3(float3 a) {
    float n = sqrtf(dot3(a, a));
    float inv = 1.0f / fmaxf(n, EPS);
    return scale3(inv, a);
}
__device__ __forceinline__ void wave_lds_fence() {
    // Intra-wave producer->consumer through LDS: compiler barrier + drain LDS ops.
    asm volatile("s_waitcnt lgkmcnt(0)" ::: "memory");
}

// record word layout: [0..2]=p0 [3..5]=p1 [6..8]=p2 [9..17]=n0,n1,n2 [18..26]=c0,c1,c2
// global fa stride: 8 float4 (128 B, line-aligned)

// ---------------- Pass 1: face-major gather, LDS-transposed coalesced stores --
__global__ __launch_bounds__(256) void gather_faces_kernel(
    const float* __restrict__ verts,
    const float* __restrict__ vnorm,
    const float* __restrict__ vcol,
    const int* __restrict__ faces,
    float4* __restrict__ fa,
    int F)
{
    __shared__ float lds[4][64 * REC_W];

    int lane = threadIdx.x & 63;
    int wv   = threadIdx.x >> 6;
    int waveBase = blockIdx.x * 256 + wv * 64;
    int f = waveBase + lane;
    float* myl = lds[wv];

    if (f < F) {
        int v0 = faces[3*f+0];
        int v1 = faces[3*f+1];
        int v2 = faces[3*f+2];

        union { float4 q[7]; float w[28]; } u;
#define PUT3(base, src, vi) \
        u.w[base+0] = src[3*vi+0]; \
        u.w[base+1] = src[3*vi+1]; \
        u.w[base+2] = src[3*vi+2];
        PUT3(0,  verts, v0)  PUT3(3,  verts, v1)  PUT3(6,  verts, v2)
        PUT3(9,  vnorm, v0)  PUT3(12, vnorm, v1)  PUT3(15, vnorm, v2)
        PUT3(18, vcol,  v0)  PUT3(21, vcol,  v1)  PUT3(24, vcol,  v2)
#undef PUT3
        u.w[27] = 0.0f;

        // write own record into LDS with xor-swizzled segment placement
#pragma unroll
        for (int s = 0; s < 7; ++s) {
            *reinterpret_cast<float4*>(&myl[lane * REC_W + ((s + lane) & 7) * 4]) = u.q[s];
        }
    }
    wave_lds_fence();

    // coalesced store phase: 8-lane groups store whole records of 8 consecutive faces
    int seg = lane & 7;
    int sub = lane >> 3;
#pragma unroll
    for (int it = 0; it < 8; ++it) {
        int pl = it * 8 + sub;          // local face 0..63
        int gf = waveBase + pl;
        if (gf < F) {
            float4 v;
            if (seg < 7)
                v = *reinterpret_cast<const float4*>(&myl[pl * REC_W + ((seg + pl) & 7) * 4]);
            else
                v = make_float4(0.f, 0.f, 0.f, 0.f);
            fa[(size_t)gf * 8 + seg] = v;
        }
    }
}

// ---------------- Pass 2: wave-cooperative line-granular gather + shade ------
__global__ __launch_bounds__(256) void phong_kernel3(
    const int* __restrict__ p2f,
    const float* __restrict__ bary,
    const float4* __restrict__ fa,
    const float* __restrict__ light_loc,
    const float* __restrict__ l_amb,
    const float* __restrict__ l_diff,
    const float* __restrict__ l_spec,
    const float* __restrict__ m_amb,
    const float* __restrict__ m_diff,
    const float* __restrict__ m_spec,
    const float* __restrict__ shin,
    const float* __restrict__ cam,
    const float* __restrict__ bg,
    float* __restrict__ out,
    int total, int hw)
{
    __shared__ float lds[4][64 * REC_W];

    int lane = threadIdx.x & 63;
    int wv   = threadIdx.x >> 6;
    int idx  = blockIdx.x * 256 + wv * 64 + lane;
    // grid sized so idx < total (total % 256 == 0)

    int f = p2f[idx];
    float b0 = bary[3*idx+0];
    float b1 = bary[3*idx+1];
    float b2 = bary[3*idx+2];
    int g = f < 0 ? 0 : f;

    float* myl = lds[wv];
    int seg = lane & 7;
    int sub = lane >> 3;

    // Phase A: cooperative gather — 8 records per instruction, 1 line per 8 lanes
#pragma unroll
    for (int it = 0; it < 8; ++it) {
        int p = it * 8 + sub;                 // pixel 0..63 within wave
        int fp = __shfl(g, p, 64);            // face id for pixel p
        float4 v = fa[(size_t)fp * 8 + seg];
        *reinterpret_cast<float4*>(&myl[p * REC_W + ((seg + p) & 7) * 4]) = v;
    }
    wave_lds_fence();

    // Phase B: each lane reads its own record (xor-swizzled → conflict-free)
    union { float4 q[7]; float w[28]; } r;
#pragma unroll
    for (int j = 0; j < 7; ++j) {
        r.q[j] = *reinterpret_cast<const float4*>(&myl[lane * REC_W + ((j + lane) & 7) * 4]);
    }
    const float* h = r.w;

    int n_b = (unsigned)idx / (unsigned)hw;
    float3 loc = ld3(light_loc, n_b);
    float3 cm  = ld3(cam, n_b);

    float3 p = make_float3(
        b0*h[0] + b1*h[3] + b2*h[6],
        b0*h[1] + b1*h[4] + b2*h[7],
        b0*h[2] + b1*h[5] + b2*h[8]);
    float3 nr = make_float3(
        b0*h[9]  + b1*h[12] + b2*h[15],
        b0*h[10] + b1*h[13] + b2*h[16],
        b0*h[11] + b1*h[14] + b2*h[17]);
    float3 tx = make_float3(
        b0*h[18] + b1*h[21] + b2*h[24],
        b0*h[19] + b1*h[22] + b2*h[25],
        b0*h[20] + b1*h[23] + b2*h[26]);

    float3 n  = norm3(nr);
    float3 tl = norm3(sub3(loc, p));
    float cos_angle = dot3(n, tl);
    float cos_pos = fmaxf(cos_angle, 0.0f);
    float smask = (cos_angle > 0.0f) ? 1.0f : 0.0f;
    float cos_m = cos_angle * smask;

    float3 vd = norm3(sub3(cm, p));
    float3 refl = add3(scale3(-1.0f, tl), scale3(2.0f * cos_m, n));
    float alpha = fmaxf(dot3(vd, refl), 0.0f) * smask;

    float sh = shin[0];
    float spec_pow;
    if (sh == 64.0f) {                // wave-uniform branch: 6 squarings
        float a2  = alpha * alpha;
        float a4  = a2 * a2;
        float a8  = a4 * a4;
        float a16 = a8 * a8;
        float a32 = a16 * a16;
        float a64 = a32 * a32;
        spec_pow = (alpha > 0.0f) ? a64 : 0.0f;
    } else {
        spec_pow = (alpha > 0.0f) ? powf(alpha, sh) : 0.0f;
    }

    float c0o = (m_amb[0]*l_amb[0] + m_diff[0]*l_diff[0]*cos_pos) * tx.x + m_spec[0]*l_spec[0]*spec_pow;
    float c1o = (m_amb[1]*l_amb[1] + m_diff[1]*l_diff[1]*cos_pos) * tx.y + m_spec[1]*l_spec[1]*spec_pow;
    float c2o = (m_amb[2]*l_amb[2] + m_diff[2]*l_diff[2]*cos_pos) * tx.z + m_spec[2]*l_spec[2]*spec_pow;

    float4 o = (f < 0) ? make_float4(bg[0], bg[1], bg[2], 0.0f)
                       : make_float4(c0o, c1o, c2o, 1.0f);
    reinterpret_cast<float4*>(out)[idx] = o;
}

// ---------------- Fallback single-pass --------------------------------------
__global__ __launch_bounds__(256) void phong_kernel1(
    const int* __restrict__ p2f,
    const float* __restrict__ bary,
    const float* __restrict__ verts,
    const float* __restrict__ vnorm,
    const float* __restrict__ vcol,
    const int* __restrict__ faces,
    const float* __restrict__ light_loc,
    const float* __restrict__ l_amb,
    const float* __restrict__ l_diff,
    const float* __restrict__ l_spec,
    const float* __restrict__ m_amb,
    const float* __restrict__ m_diff,
    const float* __restrict__ m_spec,
    const float* __restrict__ shin,
    const float* __restrict__ cam,
    const float* __restrict__ bg,
    float* __restrict__ out,
    int total, int hw)
{
    int idx = blockIdx.x * blockDim.x + threadIdx.x;
    if (idx >= total) return;

    int f = p2f[idx];
    float4 o;
    if (f < 0) {
        o = make_float4(bg[0], bg[1], bg[2], 0.0f);
    } else {
        float b0 = bary[3*idx+0];
        float b1 = bary[3*idx+1];
        float b2 = bary[3*idx+2];
        int v0 = faces[3*f+0];
        int v1 = faces[3*f+1];
        int v2 = faces[3*f+2];

        float3 p = add3(add3(scale3(b0, ld3(verts, v0)),
                             scale3(b1, ld3(verts, v1))),
                             scale3(b2, ld3(verts, v2)));
        float3 nr = add3(add3(scale3(b0, ld3(vnorm, v0)),
                              scale3(b1, ld3(vnorm, v1))),
                              scale3(b2, ld3(vnorm, v2)));
        float3 tx = add3(add3(scale3(b0, ld3(vcol, v0)),
                              scale3(b1, ld3(vcol, v1))),
                              scale3(b2, ld3(vcol, v2)));

        int n_b = (unsigned)idx / (unsigned)hw;
        float3 loc = ld3(light_loc, n_b);
        float3 cm  = ld3(cam, n_b);

        float3 n  = norm3(nr);
        float3 tl = norm3(sub3(loc, p));
        float cos_angle = dot3(n, tl);
        float cos_pos = fmaxf(cos_angle, 0.0f);
        float smask = (cos_angle > 0.0f) ? 1.0f : 0.0f;
        float cos_m = cos_angle * smask;

        float3 vd = norm3(sub3(cm, p));
        float3 refl = add3(scale3(-1.0f, tl), scale3(2.0f * cos_m, n));
        float alpha = fmaxf(dot3(vd, refl), 0.0f) * smask;
        float spec_pow = (alpha > 0.0f) ? powf(alpha, shin[0]) : 0.0f;

        float c0o = (m_amb[0]*l_amb[0] + m_diff[0]*l_diff[0]*cos_pos) * tx.x + m_spec[0]*l_spec[0]*spec_pow;
        float c1o = (m_amb[1]*l_amb[1] + m_diff[1]*l_diff[1]*cos_pos) * tx.y + m_spec[1]*l_spec[1]*spec_pow;
        float c2o = (m_amb[2]*l_amb[2] + m_diff[2]*l_diff[2]*cos_pos) * tx.z + m_spec[2]*l_spec[2]*spec_pow;
        o = make_float4(c0o, c1o, c2o, 1.0f);
    }
    reinterpret_cast<float4*>(out)[idx] = o;
}

extern "C" void kernel_launch(void* const* d_in, const int* in_sizes, int n_in,
                              void* d_out, int out_size, void* d_ws, size_t ws_size,
                              hipStream_t stream) {
    const int*   p2f       = (const int*)  d_in[0];
    const float* bary      = (const float*)d_in[1];
    const float* verts     = (const float*)d_in[2];
    const float* vnorm     = (const float*)d_in[3];
    const float* vcol      = (const float*)d_in[4];
    const int*   faces     = (const int*)  d_in[5];
    const float* light_loc = (const float*)d_in[6];
    const float* l_amb     = (const float*)d_in[7];
    const float* l_diff    = (const float*)d_in[8];
    const float* l_spec    = (const float*)d_in[9];
    const float* m_amb     = (const float*)d_in[10];
    const float* m_diff    = (const float*)d_in[11];
    const float* m_spec    = (const float*)d_in[12];
    const float* shin      = (const float*)d_in[13];
    const float* cam       = (const float*)d_in[14];
    const float* bg        = (const float*)d_in[15];
    float* out = (float*)d_out;

    int total   = in_sizes[0];         // N*H*W*K pixels (K=1)
    int n_batch = in_sizes[6] / 3;     // N
    int hw      = total / n_batch;     // H*W*K
    int F       = in_sizes[5] / 3;     // faces

    int block = 256;
    bool ws_ok = ws_size >= (size_t)F * 128;

    if (ws_ok && (total % 256) == 0) {
        float4* fa = (float4*)d_ws;
        int grid1 = (F + block - 1) / block;
        gather_faces_kernel<<<grid1, block, 0, stream>>>(verts, vnorm, vcol, faces, fa, F);
        int grid2 = total / 256;
        phong_kernel3<<<grid2, block, 0, stream>>>(
            p2f, bary, fa, light_loc,
            l_amb, l_diff, l_spec, m_amb, m_diff, m_spec, shin, cam, bg,
            out, total, hw);
    } else {
        int grid = (total + block - 1) / block;
        phong_kernel1<<<grid, block, 0, stream>>>(
            p2f, bary, verts, vnorm, vcol, faces, light_loc,
            l_amb, l_diff, l_spec, m_amb, m_diff, m_spec, shin, cam, bg,
            out, total, hw);
    }
}